// Round 3
// baseline (453.976 us; speedup 1.0000x reference)
//
#include <hip/hip_runtime.h>

// Round 3: spatial sort + per-block LDS volume bricks.
// Samples bucketed into 4096 Morton 16^3 cells by their *transformed center*
// (hist -> padded scan -> scatter; bucket groups padded to multiples of 16 so
// every block's 16 samples share one bucket). Main kernel: 1024 threads =
// 16 waves = 16 samples; block stages a zero-padded 24^3 brick (cell + halo 4)
// into LDS, then each lane's 8 trilinear taps are LDS reads (no L1 gather).
// Taps escaping the brick (Gaussian-tail offsets) fall back to masked global
// loads. Zero-filled OOB brick voxels reproduce border-zero semantics exactly.

#define VOL_N 256
#define S_PSF 64
#define NBUCKET 4096          // 16x16x16 Morton cells of 16^3 voxels
#define HALO 4
#define BRICK 24              // 16 + 2*HALO
#define BRICK_YSTR 25         // +1 pad to break bank alignment
#define BRICK_ZSTR 600        // 24*25
#define BRICK_VOX (BRICK * BRICK * BRICK)   // 13824
#define LDS_FLOATS (BRICK * BRICK_ZSTR)     // 14400 -> 57.6 KB
#define SPB 16                // samples per block (16 waves of 64)

// ---- workspace layout (ints) ----
// [0, 4096)                  histogram
// [4096, 8192)               padded bucket offsets (consumed by scatter)
// [8192, 8192 + NSLOT)       permutation (padded; -1 = empty slot)
//   NSLOT = N + SPB*NBUCKET

__device__ __forceinline__ void sample_center(const float* __restrict__ sg,
                                              const float* __restrict__ ax,
                                              int n, float& cx, float& cy, float& cz) {
    const float vx = ax[n * 6 + 0], vy = ax[n * 6 + 1], vz = ax[n * 6 + 2];
    const float tx = ax[n * 6 + 3], ty = ax[n * 6 + 4], tz = ax[n * 6 + 5];
    const float theta = sqrtf(vx * vx + vy * vy + vz * vz);
    const float kinv = 1.0f / fmaxf(theta, 1e-12f);
    const float kx = vx * kinv, ky = vy * kinv, kz = vz * kinv;
    const float ct = __cosf(theta), st = __sinf(theta);
    const float oc = 1.0f - ct;
    const float r00 = 1.0f + oc * (-(ky * ky + kz * kz));
    const float r01 = -st * kz + oc * kx * ky;
    const float r02 =  st * ky + oc * kx * kz;
    const float r10 =  st * kz + oc * kx * ky;
    const float r11 = 1.0f + oc * (-(kx * kx + kz * kz));
    const float r12 = -st * kx + oc * ky * kz;
    const float r20 = -st * ky + oc * kx * kz;
    const float r21 =  st * kx + oc * ky * kz;
    const float r22 = 1.0f + oc * (-(kx * kx + ky * ky));
    const float px = sg[n * 3 + 0] + tx;
    const float py = sg[n * 3 + 1] + ty;
    const float pz = sg[n * 3 + 2] + tz;
    cx = r00 * px + r01 * py + r02 * pz;
    cy = r10 * px + r11 * py + r12 * pz;
    cz = r20 * px + r21 * py + r22 * pz;
}

__device__ __forceinline__ void cell_of_center(float cx, float cy, float cz,
                                               int& ix, int& iy, int& iz) {
    ix = min(max((int)cx, 0), VOL_N - 1) >> 4;
    iy = min(max((int)cy, 0), VOL_N - 1) >> 4;
    iz = min(max((int)cz, 0), VOL_N - 1) >> 4;
}

__device__ __forceinline__ int morton3(int cx, int cy, int cz) {
    int m = 0;
    #pragma unroll
    for (int b = 0; b < 4; b++) {
        m |= (((cx >> b) & 1) << (3 * b))
           | (((cy >> b) & 1) << (3 * b + 1))
           | (((cz >> b) & 1) << (3 * b + 2));
    }
    return m;
}

__global__ void zero_hist_kernel(int* __restrict__ ws) {
    int i = blockIdx.x * blockDim.x + threadIdx.x;
    if (i < NBUCKET) ws[i] = 0;
}

__global__ void fill_perm_kernel(int* __restrict__ ws, int nslot) {
    int i = blockIdx.x * blockDim.x + threadIdx.x;
    if (i < nslot) ws[2 * NBUCKET + i] = -1;
}

__global__ void hist_kernel(const float* __restrict__ sg, const float* __restrict__ ax,
                            int* __restrict__ ws, int N) {
    int n = blockIdx.x * blockDim.x + threadIdx.x;
    if (n >= N) return;
    float cx, cy, cz;
    sample_center(sg, ax, n, cx, cy, cz);
    int ix, iy, iz;
    cell_of_center(cx, cy, cz, ix, iy, iz);
    atomicAdd(&ws[morton3(ix, iy, iz)], 1);
}

__global__ __launch_bounds__(1024) void scan_kernel(int* __restrict__ ws) {
    // exclusive prefix sum of PADDED counts (pad each bucket to multiple of 16)
    __shared__ int tmp[1024];
    const int t = threadIdx.x;
    int p0 = (ws[t * 4 + 0] + SPB - 1) & ~(SPB - 1);
    int p1 = (ws[t * 4 + 1] + SPB - 1) & ~(SPB - 1);
    int p2 = (ws[t * 4 + 2] + SPB - 1) & ~(SPB - 1);
    int p3 = (ws[t * 4 + 3] + SPB - 1) & ~(SPB - 1);
    int s = p0 + p1 + p2 + p3;
    tmp[t] = s;
    __syncthreads();
    for (int off = 1; off < 1024; off <<= 1) {
        int v = (t >= off) ? tmp[t - off] : 0;
        __syncthreads();
        tmp[t] += v;
        __syncthreads();
    }
    int excl = tmp[t] - s;
    ws[NBUCKET + t * 4 + 0] = excl;
    ws[NBUCKET + t * 4 + 1] = excl + p0;
    ws[NBUCKET + t * 4 + 2] = excl + p0 + p1;
    ws[NBUCKET + t * 4 + 3] = excl + p0 + p1 + p2;
}

__global__ void scatter_kernel(const float* __restrict__ sg, const float* __restrict__ ax,
                               int* __restrict__ ws, int N) {
    int n = blockIdx.x * blockDim.x + threadIdx.x;
    if (n >= N) return;
    float cx, cy, cz;
    sample_center(sg, ax, n, cx, cy, cz);
    int ix, iy, iz;
    cell_of_center(cx, cy, cz, ix, iy, iz);
    int b = morton3(ix, iy, iz);
    int pos = atomicAdd(&ws[NBUCKET + b], 1);
    ws[2 * NBUCKET + pos] = n;
}

__global__ __launch_bounds__(1024, 8) void psf_sample_kernel(
    const float* __restrict__ vol,        // [256][256][256] (z,y,x)
    const float* __restrict__ sampleGrid, // [N][3]
    const float* __restrict__ ax,         // [N][6]
    const float* __restrict__ bound,      // [N][2][3]
    const float* __restrict__ invcov,     // [3][3]
    const float* __restrict__ xyz_psf,    // [N][64][3]
    const int* __restrict__ perm,         // padded permutation (or null)
    float* __restrict__ out,              // [N]
    int N)
{
    __shared__ float lds[LDS_FLOATS];

    const int tid = threadIdx.x;
    const int lane = tid & 63;
    const int wave = tid >> 6;

    // XCD-contiguous swizzle
    int bid = blockIdx.x;
    const int nb = gridDim.x;
    if ((nb & 7) == 0) bid = (bid & 7) * (nb >> 3) + (bid >> 3);

    const int slot_base = bid * SPB;
    const int n0 = perm ? perm[slot_base] : (slot_base < N ? slot_base : -1);
    if (n0 < 0) return;  // whole block is padding (uniform)

    // brick origin from the block's first sample's cell
    float ccx, ccy, ccz;
    sample_center(sampleGrid, ax, n0, ccx, ccy, ccz);
    int cix, ciy, ciz;
    cell_of_center(ccx, ccy, ccz, cix, ciy, ciz);
    const int bx0 = (cix << 4) - HALO;
    const int by0 = (ciy << 4) - HALO;
    const int bz0 = (ciz << 4) - HALO;

    // ---- stage brick (zero-padded outside volume) ----
    for (int t = tid; t < BRICK_VOX; t += 1024) {
        const int z = t / (BRICK * BRICK);
        const int r = t - z * (BRICK * BRICK);
        const int y = r / BRICK;
        const int x = r - y * BRICK;
        const int gx = bx0 + x, gy = by0 + y, gz = bz0 + z;
        float v = 0.0f;
        if ((unsigned)gx < VOL_N && (unsigned)gy < VOL_N && (unsigned)gz < VOL_N)
            v = vol[(gz << 16) + (gy << 8) + gx];
        lds[z * BRICK_ZSTR + y * BRICK_YSTR + x] = v;
    }
    __syncthreads();

    // ---- per-wave sample ----
    const int slot = slot_base + wave;
    const int n = perm ? perm[slot] : (slot < N ? slot : -1);
    if (n < 0) return;  // pad wave (no more barriers below)

    const float vx = ax[n * 6 + 0], vy = ax[n * 6 + 1], vz = ax[n * 6 + 2];
    const float tx = ax[n * 6 + 3], ty = ax[n * 6 + 4], tz = ax[n * 6 + 5];
    const float theta = sqrtf(vx * vx + vy * vy + vz * vz);
    const float kinv = 1.0f / fmaxf(theta, 1e-12f);
    const float kx = vx * kinv, ky = vy * kinv, kz = vz * kinv;
    const float ct = __cosf(theta), st = __sinf(theta);
    const float oc = 1.0f - ct;
    const float r00 = 1.0f + oc * (-(ky * ky + kz * kz));
    const float r01 = -st * kz + oc * kx * ky;
    const float r02 =  st * ky + oc * kx * kz;
    const float r10 =  st * kz + oc * kx * ky;
    const float r11 = 1.0f + oc * (-(kx * kx + kz * kz));
    const float r12 = -st * kx + oc * ky * kz;
    const float r20 = -st * ky + oc * kx * kz;
    const float r21 =  st * kx + oc * ky * kz;
    const float r22 = 1.0f + oc * (-(kx * kx + ky * ky));
    const float px = sampleGrid[n * 3 + 0] + tx;
    const float py = sampleGrid[n * 3 + 1] + ty;
    const float pz = sampleGrid[n * 3 + 2] + tz;
    const float cx = r00 * px + r01 * py + r02 * pz;
    const float cy = r10 * px + r11 * py + r12 * pz;
    const float cz = r20 * px + r21 * py + r22 * pz;

    const float hx = (bound[n * 6 + 3] - bound[n * 6 + 0]) * 0.5f;
    const float hy = (bound[n * 6 + 4] - bound[n * 6 + 1]) * 0.5f;
    const float hz = (bound[n * 6 + 5] - bound[n * 6 + 2]) * 0.5f;

    const float m00 = invcov[0], m01 = invcov[1], m02 = invcov[2];
    const float m10 = invcov[3], m11 = invcov[4], m12 = invcov[5];
    const float m20 = invcov[6], m21 = invcov[7], m22 = invcov[8];

    const long long pbase = ((long long)n * S_PSF + lane) * 3;
    const float ox = xyz_psf[pbase + 0] * hx;
    const float oy = xyz_psf[pbase + 1] * hy;
    const float oz = xyz_psf[pbase + 2] * hz;

    const float scale = (float)VOL_N / (float)(VOL_N - 1);
    const float ix = (cx + ox) * scale - 0.5f;
    const float iy = (cy + oy) * scale - 0.5f;
    const float iz = (cz + oz) * scale - 0.5f;

    const float x0f = floorf(ix), y0f = floorf(iy), z0f = floorf(iz);
    const float fx = ix - x0f, fy = iy - y0f, fz = iz - z0f;
    const int x0 = (int)x0f, y0 = (int)y0f, z0 = (int)z0f;

    const float wx0 = 1.0f - fx, wx1 = fx;
    const float wy0 = 1.0f - fy, wy1 = fy;
    const float wz0 = 1.0f - fz, wz1 = fz;

    const int rx = x0 - bx0, ry = y0 - by0, rz = z0 - bz0;
    const bool fast = (unsigned)rx <= (BRICK - 2) && (unsigned)ry <= (BRICK - 2)
                   && (unsigned)rz <= (BRICK - 2);

    float acc;
    if (fast) {
        const int a = rz * BRICK_ZSTR + ry * BRICK_YSTR + rx;
        const float v000 = lds[a];
        const float v001 = lds[a + 1];
        const float v010 = lds[a + BRICK_YSTR];
        const float v011 = lds[a + BRICK_YSTR + 1];
        const float v100 = lds[a + BRICK_ZSTR];
        const float v101 = lds[a + BRICK_ZSTR + 1];
        const float v110 = lds[a + BRICK_ZSTR + BRICK_YSTR];
        const float v111 = lds[a + BRICK_ZSTR + BRICK_YSTR + 1];
        acc = v000 * (wx0 * wy0 * wz0) + v001 * (wx1 * wy0 * wz0)
            + v010 * (wx0 * wy1 * wz0) + v011 * (wx1 * wy1 * wz0)
            + v100 * (wx0 * wy0 * wz1) + v101 * (wx1 * wy0 * wz1)
            + v110 * (wx0 * wy1 * wz1) + v111 * (wx1 * wy1 * wz1);
    } else {
        const int x1 = x0 + 1, y1 = y0 + 1, z1 = z0 + 1;
        const bool vx0 = (unsigned)x0 < VOL_N, vx1 = (unsigned)x1 < VOL_N;
        const bool vy0 = (unsigned)y0 < VOL_N, vy1 = (unsigned)y1 < VOL_N;
        const bool vz0 = (unsigned)z0 < VOL_N, vz1 = (unsigned)z1 < VOL_N;
        const int xc0 = min(max(x0, 0), VOL_N - 1), xc1 = min(max(x1, 0), VOL_N - 1);
        const int yc0 = min(max(y0, 0), VOL_N - 1), yc1 = min(max(y1, 0), VOL_N - 1);
        const int zc0 = min(max(z0, 0), VOL_N - 1), zc1 = min(max(z1, 0), VOL_N - 1);
        const int zo0 = zc0 << 16, zo1 = zc1 << 16;
        const int yo0 = yc0 << 8, yo1 = yc1 << 8;
        const float v000 = vol[zo0 + yo0 + xc0];
        const float v001 = vol[zo0 + yo0 + xc1];
        const float v010 = vol[zo0 + yo1 + xc0];
        const float v011 = vol[zo0 + yo1 + xc1];
        const float v100 = vol[zo1 + yo0 + xc0];
        const float v101 = vol[zo1 + yo0 + xc1];
        const float v110 = vol[zo1 + yo1 + xc0];
        const float v111 = vol[zo1 + yo1 + xc1];
        acc = 0.0f;
        acc += (vx0 && vy0 && vz0) ? v000 * (wx0 * wy0 * wz0) : 0.0f;
        acc += (vx1 && vy0 && vz0) ? v001 * (wx1 * wy0 * wz0) : 0.0f;
        acc += (vx0 && vy1 && vz0) ? v010 * (wx0 * wy1 * wz0) : 0.0f;
        acc += (vx1 && vy1 && vz0) ? v011 * (wx1 * wy1 * wz0) : 0.0f;
        acc += (vx0 && vy0 && vz1) ? v100 * (wx0 * wy0 * wz1) : 0.0f;
        acc += (vx1 && vy0 && vz1) ? v101 * (wx1 * wy0 * wz1) : 0.0f;
        acc += (vx0 && vy1 && vz1) ? v110 * (wx0 * wy1 * wz1) : 0.0f;
        acc += (vx1 && vy1 && vz1) ? v111 * (wx1 * wy1 * wz1) : 0.0f;
    }

    const float qx = m00 * ox + m01 * oy + m02 * oz;
    const float qy = m10 * ox + m11 * oy + m12 * oz;
    const float qz = m20 * ox + m21 * oy + m22 * oz;
    const float q = ox * qx + oy * qy + oz * qz;
    const float w = __expf(-0.5f * q);

    float num = acc * w;
    float den = w;
    #pragma unroll
    for (int m = 32; m >= 1; m >>= 1) {
        num += __shfl_xor(num, m, 64);
        den += __shfl_xor(den, m, 64);
    }
    if (lane == 0) out[n] = num / den;
}

extern "C" void kernel_launch(void* const* d_in, const int* in_sizes, int n_in,
                              void* d_out, int out_size, void* d_ws, size_t ws_size,
                              hipStream_t stream) {
    const float* x        = (const float*)d_in[0];
    const float* sg       = (const float*)d_in[1];
    const float* ax       = (const float*)d_in[2];
    const float* bound    = (const float*)d_in[3];
    const float* invcov   = (const float*)d_in[4];
    const float* xyz_psf  = (const float*)d_in[5];
    float* out            = (float*)d_out;

    const int N = in_sizes[1] / 3;                 // sampleGrid is [N][3]
    const int nslot = N + SPB * NBUCKET;           // padded permutation size
    const size_t ws_needed = (size_t)(2 * NBUCKET + nslot) * sizeof(int);

    int* perm = nullptr;
    int nblocks;
    if (ws_size >= ws_needed) {
        int* ws = (int*)d_ws;
        zero_hist_kernel<<<(NBUCKET + 255) / 256, 256, 0, stream>>>(ws);
        fill_perm_kernel<<<(nslot + 1023) / 1024, 1024, 0, stream>>>(ws, nslot);
        hist_kernel<<<(N + 255) / 256, 256, 0, stream>>>(sg, ax, ws, N);
        scan_kernel<<<1, 1024, 0, stream>>>(ws);
        scatter_kernel<<<(N + 255) / 256, 256, 0, stream>>>(sg, ax, ws, N);
        perm = ws + 2 * NBUCKET;
        nblocks = nslot / SPB;
    } else {
        nblocks = (N + SPB - 1) / SPB;
    }

    psf_sample_kernel<<<nblocks, 1024, 0, stream>>>(x, sg, ax, bound, invcov,
                                                    xyz_psf, perm, out, N);
}

// Round 5
// 375.776 us; speedup vs baseline: 1.2081x; 1.2081x over previous
//
#include <hip/hip_runtime.h>

// Round 5 (= round 4 with the nontemporal-builtin type fix): one wave per
// sample, spatial sort, plus a pre-built redundant x-pair volume
// pairs[z][y][x] = (v[z][y][x], v[z][y][x+1]) as aligned float2 in d_ws, so
// each (z,y) row of the trilinear stencil is ONE dwordx2 gather instead of
// two dword gathers: 4 vmem instructions per lane instead of 8. Edge x-clamp
// handled by cndmask selects (exact fp32).

#define VOL_N 256
#define S_PSF 64
#define NBUCKET 4096   // 16x16x16 cells of 16^3 voxels
#define PAIRS_ELEMS (1 << 24)            // 256^3
#define PAIRS_BYTES ((size_t)PAIRS_ELEMS * 8)

typedef float vf4 __attribute__((ext_vector_type(4)));

// ---- d_ws layout ----
// [0, PAIRS_BYTES)                float2 pair table (if ws large enough)
// then ints: hist[4096] | offsets[4096] | perm[N]

__device__ __forceinline__ int bucket_of(const float* __restrict__ sg, int n) {
    int cx = min(max((int)sg[n * 3 + 0], 0), VOL_N - 1) >> 4;
    int cy = min(max((int)sg[n * 3 + 1], 0), VOL_N - 1) >> 4;
    int cz = min(max((int)sg[n * 3 + 2], 0), VOL_N - 1) >> 4;
    int m = 0;
    #pragma unroll
    for (int b = 0; b < 4; b++) {
        m |= (((cx >> b) & 1) << (3 * b))
           | (((cy >> b) & 1) << (3 * b + 1))
           | (((cz >> b) & 1) << (3 * b + 2));
    }
    return m;
}

__global__ void zero_hist_kernel(int* __restrict__ ws) {
    int i = blockIdx.x * blockDim.x + threadIdx.x;
    if (i < NBUCKET) ws[i] = 0;
}

__global__ void hist_kernel(const float* __restrict__ sg, int* __restrict__ ws, int N) {
    int n = blockIdx.x * blockDim.x + threadIdx.x;
    if (n >= N) return;
    atomicAdd(&ws[bucket_of(sg, n)], 1);
}

__global__ __launch_bounds__(1024) void scan_kernel(int* __restrict__ ws) {
    __shared__ int tmp[1024];
    const int t = threadIdx.x;
    int h0 = ws[t * 4 + 0], h1 = ws[t * 4 + 1], h2 = ws[t * 4 + 2], h3 = ws[t * 4 + 3];
    int s = h0 + h1 + h2 + h3;
    tmp[t] = s;
    __syncthreads();
    for (int off = 1; off < 1024; off <<= 1) {
        int v = (t >= off) ? tmp[t - off] : 0;
        __syncthreads();
        tmp[t] += v;
        __syncthreads();
    }
    int excl = tmp[t] - s;
    ws[NBUCKET + t * 4 + 0] = excl;
    ws[NBUCKET + t * 4 + 1] = excl + h0;
    ws[NBUCKET + t * 4 + 2] = excl + h0 + h1;
    ws[NBUCKET + t * 4 + 3] = excl + h0 + h1 + h2;
}

__global__ void scatter_kernel(const float* __restrict__ sg, int* __restrict__ ws, int N) {
    int n = blockIdx.x * blockDim.x + threadIdx.x;
    if (n >= N) return;
    int b = bucket_of(sg, n);
    int pos = atomicAdd(&ws[NBUCKET + b], 1);
    ws[2 * NBUCKET + pos] = n;
}

// Build pairs[g] = (vol[g], vol[g+1 within row, else dup]); each thread does
// 4 consecutive x (one float4 read + one scalar, two nontemporal vf4 writes).
__global__ __launch_bounds__(256) void build_pairs_kernel(
    const float* __restrict__ vol, float* __restrict__ pairs) {
    const int g4 = blockIdx.x * blockDim.x + threadIdx.x;   // quad index
    const int g = g4 << 2;
    const vf4 v = *(const vf4*)(vol + g);
    const int x = g & (VOL_N - 1);
    const float nxt = (x == VOL_N - 4) ? v.w : __builtin_nontemporal_load(vol + g + 4);
    vf4* dst = (vf4*)(pairs + (size_t)g * 2);
    vf4 a; a.x = v.x; a.y = v.y; a.z = v.y; a.w = v.z;
    vf4 b; b.x = v.z; b.y = v.w; b.z = v.w; b.w = nxt;
    __builtin_nontemporal_store(a, dst);
    __builtin_nontemporal_store(b, dst + 1);
}

template <bool USE_PAIRS>
__global__ __launch_bounds__(256, 4) void psf_sample_kernel(
    const float* __restrict__ vol,        // [256][256][256] (z,y,x)
    const float2* __restrict__ pairs,     // x-pair table (USE_PAIRS)
    const float* __restrict__ sampleGrid, // [N][3]
    const float* __restrict__ ax,         // [N][6]
    const float* __restrict__ bound,      // [N][2][3]
    const float* __restrict__ invcov,     // [3][3]
    const float* __restrict__ xyz_psf,    // [N][64][3]
    const int* __restrict__ perm,         // sorted pos -> n (or null)
    float* __restrict__ out,              // [N]
    int N)
{
    const int lane = threadIdx.x & 63;

    // XCD-contiguous swizzle so each XCD sweeps a contiguous sorted range
    int bid = blockIdx.x;
    const int nb = gridDim.x;
    if ((nb & 7) == 0) bid = (bid & 7) * (nb >> 3) + (bid >> 3);

    const int i = bid * (blockDim.x >> 6) + (threadIdx.x >> 6);
    if (i >= N) return;
    const int n = perm ? perm[i] : i;

    // ---- wave-uniform per-sample setup ----
    const float vx = ax[n * 6 + 0], vy = ax[n * 6 + 1], vz = ax[n * 6 + 2];
    const float tx = ax[n * 6 + 3], ty = ax[n * 6 + 4], tz = ax[n * 6 + 5];

    const float theta = sqrtf(vx * vx + vy * vy + vz * vz);
    const float kinv = 1.0f / fmaxf(theta, 1e-12f);
    const float kx = vx * kinv, ky = vy * kinv, kz = vz * kinv;
    const float ct = __cosf(theta), st = __sinf(theta);
    const float oc = 1.0f - ct;

    const float r00 = 1.0f + oc * (-(ky * ky + kz * kz));
    const float r01 = -st * kz + oc * kx * ky;
    const float r02 =  st * ky + oc * kx * kz;
    const float r10 =  st * kz + oc * kx * ky;
    const float r11 = 1.0f + oc * (-(kx * kx + kz * kz));
    const float r12 = -st * kx + oc * ky * kz;
    const float r20 = -st * ky + oc * kx * kz;
    const float r21 =  st * kx + oc * ky * kz;
    const float r22 = 1.0f + oc * (-(kx * kx + ky * ky));

    const float px = sampleGrid[n * 3 + 0] + tx;
    const float py = sampleGrid[n * 3 + 1] + ty;
    const float pz = sampleGrid[n * 3 + 2] + tz;

    const float cx = r00 * px + r01 * py + r02 * pz;
    const float cy = r10 * px + r11 * py + r12 * pz;
    const float cz = r20 * px + r21 * py + r22 * pz;

    const float hx = (bound[n * 6 + 3] - bound[n * 6 + 0]) * 0.5f;
    const float hy = (bound[n * 6 + 4] - bound[n * 6 + 1]) * 0.5f;
    const float hz = (bound[n * 6 + 5] - bound[n * 6 + 2]) * 0.5f;

    const float m00 = invcov[0], m01 = invcov[1], m02 = invcov[2];
    const float m10 = invcov[3], m11 = invcov[4], m12 = invcov[5];
    const float m20 = invcov[6], m21 = invcov[7], m22 = invcov[8];

    // ---- per-lane PSF point ----
    const long long base = ((long long)n * S_PSF + lane) * 3;
    const float ox = xyz_psf[base + 0] * hx;
    const float oy = xyz_psf[base + 1] * hy;
    const float oz = xyz_psf[base + 2] * hz;

    const float scale = (float)VOL_N / (float)(VOL_N - 1);
    const float ix = (cx + ox) * scale - 0.5f;
    const float iy = (cy + oy) * scale - 0.5f;
    const float iz = (cz + oz) * scale - 0.5f;

    const float x0f = floorf(ix), y0f = floorf(iy), z0f = floorf(iz);
    const float fx = ix - x0f, fy = iy - y0f, fz = iz - z0f;
    const int x0 = (int)x0f, y0 = (int)y0f, z0 = (int)z0f;
    const int x1 = x0 + 1, y1 = y0 + 1, z1 = z0 + 1;

    const bool vx0 = (unsigned)x0 < (unsigned)VOL_N;
    const bool vx1 = (unsigned)x1 < (unsigned)VOL_N;
    const bool vy0 = (unsigned)y0 < (unsigned)VOL_N;
    const bool vy1 = (unsigned)y1 < (unsigned)VOL_N;
    const bool vz0 = (unsigned)z0 < (unsigned)VOL_N;
    const bool vz1 = (unsigned)z1 < (unsigned)VOL_N;

    const int yc0 = min(max(y0, 0), VOL_N - 1);
    const int yc1 = min(max(y1, 0), VOL_N - 1);
    const int zc0 = min(max(z0, 0), VOL_N - 1);
    const int zc1 = min(max(z1, 0), VOL_N - 1);
    const int zo0 = zc0 << 16, zo1 = zc1 << 16;
    const int yo0 = yc0 << 8, yo1 = yc1 << 8;

    float v000, v001, v010, v011, v100, v101, v110, v111;
    if (USE_PAIRS) {
        // one dwordx2 gather per (z,y) row; selects fix the x-clamp edges
        const int xg = min(max(x0, 0), VOL_N - 2);
        const int dx = x0 - xg;              // -1 (x0==-1), 0, or +1 (x0==255)
        const bool hi = (dx == 1), lo = (dx == -1);
        const float2 p00 = pairs[zo0 + yo0 + xg];
        const float2 p01 = pairs[zo0 + yo1 + xg];
        const float2 p10 = pairs[zo1 + yo0 + xg];
        const float2 p11 = pairs[zo1 + yo1 + xg];
        v000 = hi ? p00.y : p00.x;  v001 = lo ? p00.x : p00.y;
        v010 = hi ? p01.y : p01.x;  v011 = lo ? p01.x : p01.y;
        v100 = hi ? p10.y : p10.x;  v101 = lo ? p10.x : p10.y;
        v110 = hi ? p11.y : p11.x;  v111 = lo ? p11.x : p11.y;
    } else {
        const int xc0 = min(max(x0, 0), VOL_N - 1);
        const int xc1 = min(max(x1, 0), VOL_N - 1);
        v000 = vol[zo0 + yo0 + xc0];
        v001 = vol[zo0 + yo0 + xc1];
        v010 = vol[zo0 + yo1 + xc0];
        v011 = vol[zo0 + yo1 + xc1];
        v100 = vol[zo1 + yo0 + xc0];
        v101 = vol[zo1 + yo0 + xc1];
        v110 = vol[zo1 + yo1 + xc0];
        v111 = vol[zo1 + yo1 + xc1];
    }

    const float wx0 = 1.0f - fx, wx1 = fx;
    const float wy0 = 1.0f - fy, wy1 = fy;
    const float wz0 = 1.0f - fz, wz1 = fz;

    float acc = 0.0f;
    acc += (vx0 && vy0 && vz0) ? v000 * (wx0 * wy0 * wz0) : 0.0f;
    acc += (vx1 && vy0 && vz0) ? v001 * (wx1 * wy0 * wz0) : 0.0f;
    acc += (vx0 && vy1 && vz0) ? v010 * (wx0 * wy1 * wz0) : 0.0f;
    acc += (vx1 && vy1 && vz0) ? v011 * (wx1 * wy1 * wz0) : 0.0f;
    acc += (vx0 && vy0 && vz1) ? v100 * (wx0 * wy0 * wz1) : 0.0f;
    acc += (vx1 && vy0 && vz1) ? v101 * (wx1 * wy0 * wz1) : 0.0f;
    acc += (vx0 && vy1 && vz1) ? v110 * (wx0 * wy1 * wz1) : 0.0f;
    acc += (vx1 && vy1 && vz1) ? v111 * (wx1 * wy1 * wz1) : 0.0f;

    const float qx = m00 * ox + m01 * oy + m02 * oz;
    const float qy = m10 * ox + m11 * oy + m12 * oz;
    const float qz = m20 * ox + m21 * oy + m22 * oz;
    const float q = ox * qx + oy * qy + oz * qz;
    const float w = __expf(-0.5f * q);

    float num = acc * w;
    float den = w;
    #pragma unroll
    for (int m = 32; m >= 1; m >>= 1) {
        num += __shfl_xor(num, m, 64);
        den += __shfl_xor(den, m, 64);
    }
    if (lane == 0) out[n] = num / den;
}

extern "C" void kernel_launch(void* const* d_in, const int* in_sizes, int n_in,
                              void* d_out, int out_size, void* d_ws, size_t ws_size,
                              hipStream_t stream) {
    const float* x        = (const float*)d_in[0];
    const float* sg       = (const float*)d_in[1];
    const float* ax       = (const float*)d_in[2];
    const float* bound    = (const float*)d_in[3];
    const float* invcov   = (const float*)d_in[4];
    const float* xyz_psf  = (const float*)d_in[5];
    float* out            = (float*)d_out;

    const int N = in_sizes[1] / 3;           // sampleGrid is [N][3]
    const size_t sort_bytes = (size_t)(2 * NBUCKET + N) * sizeof(int);

    const bool use_pairs = ws_size >= PAIRS_BYTES + sort_bytes;
    const bool use_sort  = use_pairs || ws_size >= sort_bytes;

    float* pairs = use_pairs ? (float*)d_ws : nullptr;
    int* sort_ws = use_pairs ? (int*)((char*)d_ws + PAIRS_BYTES) : (int*)d_ws;

    int* perm = nullptr;
    if (use_sort) {
        zero_hist_kernel<<<(NBUCKET + 255) / 256, 256, 0, stream>>>(sort_ws);
        hist_kernel<<<(N + 255) / 256, 256, 0, stream>>>(sg, sort_ws, N);
        scan_kernel<<<1, 1024, 0, stream>>>(sort_ws);
        scatter_kernel<<<(N + 255) / 256, 256, 0, stream>>>(sg, sort_ws, N);
        perm = sort_ws + 2 * NBUCKET;
    }
    if (use_pairs) {
        build_pairs_kernel<<<(PAIRS_ELEMS / 4) / 256, 256, 0, stream>>>(x, pairs);
    }

    dim3 block(256);
    dim3 grid((N + 3) / 4);                  // 4 waves (samples) per block
    if (use_pairs) {
        psf_sample_kernel<true><<<grid, block, 0, stream>>>(
            x, (const float2*)pairs, sg, ax, bound, invcov, xyz_psf, perm, out, N);
    } else {
        psf_sample_kernel<false><<<grid, block, 0, stream>>>(
            x, nullptr, sg, ax, bound, invcov, xyz_psf, perm, out, N);
    }
}

// Round 6
// 329.273 us; speedup vs baseline: 1.3787x; 1.1412x over previous
//
#include <hip/hip_runtime.h>

// Round 6: (a) readfirstlane-scalarized per-sample setup (s_load instead of
// ~25 broadcast vector loads per wave); (b) fp16 quad table
// tbl[z][y][x] = {v[y][x], v[y][x+1], v[y+1][x], v[y+1][x+1]} (8B), edges
// duplicated at build, so trilinear = 2 dwordx2 gathers per point (z0/z1
// planes). Spatial sort retained. Masks still implement border-zero exactly;
// only lo-side (x0<0 / y0<0) needs slot-selects.

#define VOL_N 256
#define S_PSF 64
#define NBUCKET 4096   // 16x16x16 cells of 16^3 voxels
#define TBL_ELEMS (1 << 24)                  // 256^3 entries
#define TBL_BYTES ((size_t)TBL_ELEMS * 8)    // 128 MB

typedef float vf4 __attribute__((ext_vector_type(4)));
typedef _Float16 vh4 __attribute__((ext_vector_type(4)));
typedef _Float16 vh8 __attribute__((ext_vector_type(8)));

// ---- d_ws layout ----
// [0, TBL_BYTES)      fp16 quad table (if ws large enough)
// then ints: hist[4096] | offsets[4096] | perm[N]

__device__ __forceinline__ int bucket_of(const float* __restrict__ sg, int n) {
    int cx = min(max((int)sg[n * 3 + 0], 0), VOL_N - 1) >> 4;
    int cy = min(max((int)sg[n * 3 + 1], 0), VOL_N - 1) >> 4;
    int cz = min(max((int)sg[n * 3 + 2], 0), VOL_N - 1) >> 4;
    int m = 0;
    #pragma unroll
    for (int b = 0; b < 4; b++) {
        m |= (((cx >> b) & 1) << (3 * b))
           | (((cy >> b) & 1) << (3 * b + 1))
           | (((cz >> b) & 1) << (3 * b + 2));
    }
    return m;
}

__global__ void zero_hist_kernel(int* __restrict__ ws) {
    int i = blockIdx.x * blockDim.x + threadIdx.x;
    if (i < NBUCKET) ws[i] = 0;
}

__global__ void hist_kernel(const float* __restrict__ sg, int* __restrict__ ws, int N) {
    int n = blockIdx.x * blockDim.x + threadIdx.x;
    if (n >= N) return;
    atomicAdd(&ws[bucket_of(sg, n)], 1);
}

__global__ __launch_bounds__(1024) void scan_kernel(int* __restrict__ ws) {
    __shared__ int tmp[1024];
    const int t = threadIdx.x;
    int h0 = ws[t * 4 + 0], h1 = ws[t * 4 + 1], h2 = ws[t * 4 + 2], h3 = ws[t * 4 + 3];
    int s = h0 + h1 + h2 + h3;
    tmp[t] = s;
    __syncthreads();
    for (int off = 1; off < 1024; off <<= 1) {
        int v = (t >= off) ? tmp[t - off] : 0;
        __syncthreads();
        tmp[t] += v;
        __syncthreads();
    }
    int excl = tmp[t] - s;
    ws[NBUCKET + t * 4 + 0] = excl;
    ws[NBUCKET + t * 4 + 1] = excl + h0;
    ws[NBUCKET + t * 4 + 2] = excl + h0 + h1;
    ws[NBUCKET + t * 4 + 3] = excl + h0 + h1 + h2;
}

__global__ void scatter_kernel(const float* __restrict__ sg, int* __restrict__ ws, int N) {
    int n = blockIdx.x * blockDim.x + threadIdx.x;
    if (n >= N) return;
    int b = bucket_of(sg, n);
    int pos = atomicAdd(&ws[NBUCKET + b], 1);
    ws[2 * NBUCKET + pos] = n;
}

// Build fp16 quad table. Thread handles 4 consecutive x at one (z,y):
// 2 x float4 row reads (+1 scalar each for x+4), 2 x 16B nontemporal writes.
// x=255 / y=255 neighbors are duplicated (clamped) so the hi-side edge needs
// no select in the sampling kernel.
__global__ __launch_bounds__(256) void build_quad_kernel(
    const float* __restrict__ vol, vh4* __restrict__ tbl) {
    const int t = blockIdx.x * 256 + threadIdx.x;   // [0, 256*256*64)
    const int x4 = (t & 63) << 2;
    const int y = (t >> 6) & 255;
    const int z = t >> 14;
    const float* r0 = vol + (z << 16) + (y << 8);
    const float* r1 = vol + (z << 16) + (min(y + 1, VOL_N - 1) << 8);
    const vf4 a = *(const vf4*)(r0 + x4);
    const vf4 b = *(const vf4*)(r1 + x4);
    const float a4 = (x4 == VOL_N - 4) ? a.w : r0[x4 + 4];
    const float b4 = (x4 == VOL_N - 4) ? b.w : r1[x4 + 4];

    union { vh8 h; vf4 f; } o0, o1;
    o0.h = (vh8){(_Float16)a.x, (_Float16)a.y, (_Float16)b.x, (_Float16)b.y,
                 (_Float16)a.y, (_Float16)a.z, (_Float16)b.y, (_Float16)b.z};
    o1.h = (vh8){(_Float16)a.z, (_Float16)a.w, (_Float16)b.z, (_Float16)b.w,
                 (_Float16)a.w, (_Float16)a4,  (_Float16)b.w, (_Float16)b4};
    vf4* dst = (vf4*)(tbl + ((z << 16) + (y << 8) + x4));
    __builtin_nontemporal_store(o0.f, dst);
    __builtin_nontemporal_store(o1.f, dst + 1);
}

template <bool USE_TBL>
__global__ __launch_bounds__(256, 4) void psf_sample_kernel(
    const float* __restrict__ vol,        // [256][256][256] (z,y,x)
    const vh4* __restrict__ tbl,          // fp16 quad table (USE_TBL)
    const float* __restrict__ sampleGrid, // [N][3]
    const float* __restrict__ ax,         // [N][6]
    const float* __restrict__ bound,      // [N][2][3]
    const float* __restrict__ invcov,     // [3][3]
    const float* __restrict__ xyz_psf,    // [N][64][3]
    const int* __restrict__ perm,         // sorted pos -> n (or null)
    float* __restrict__ out,              // [N]
    int N)
{
    const int lane = threadIdx.x & 63;

    // XCD-contiguous swizzle so each XCD sweeps a contiguous sorted range
    int bid = blockIdx.x;
    const int nb = gridDim.x;
    if ((nb & 7) == 0) bid = (bid & 7) * (nb >> 3) + (bid >> 3);

    const int i = bid * (blockDim.x >> 6) + (threadIdx.x >> 6);
    if (i >= N) return;
    // n is wave-uniform; force it into an SGPR so all per-sample parameter
    // loads become s_load (SMEM) instead of 64-lane broadcast vector loads.
    const int n = __builtin_amdgcn_readfirstlane(perm ? perm[i] : i);

    // ---- wave-uniform per-sample setup (scalar loads, uniform VALU math) ----
    const float vx = ax[n * 6 + 0], vy = ax[n * 6 + 1], vz = ax[n * 6 + 2];
    const float tx = ax[n * 6 + 3], ty = ax[n * 6 + 4], tz = ax[n * 6 + 5];

    const float theta = sqrtf(vx * vx + vy * vy + vz * vz);
    const float kinv = 1.0f / fmaxf(theta, 1e-12f);
    const float kx = vx * kinv, ky = vy * kinv, kz = vz * kinv;
    const float ct = __cosf(theta), st = __sinf(theta);
    const float oc = 1.0f - ct;

    const float r00 = 1.0f + oc * (-(ky * ky + kz * kz));
    const float r01 = -st * kz + oc * kx * ky;
    const float r02 =  st * ky + oc * kx * kz;
    const float r10 =  st * kz + oc * kx * ky;
    const float r11 = 1.0f + oc * (-(kx * kx + kz * kz));
    const float r12 = -st * kx + oc * ky * kz;
    const float r20 = -st * ky + oc * kx * kz;
    const float r21 =  st * kx + oc * ky * kz;
    const float r22 = 1.0f + oc * (-(kx * kx + ky * ky));

    const float px = sampleGrid[n * 3 + 0] + tx;
    const float py = sampleGrid[n * 3 + 1] + ty;
    const float pz = sampleGrid[n * 3 + 2] + tz;

    const float cx = r00 * px + r01 * py + r02 * pz;
    const float cy = r10 * px + r11 * py + r12 * pz;
    const float cz = r20 * px + r21 * py + r22 * pz;

    const float hx = (bound[n * 6 + 3] - bound[n * 6 + 0]) * 0.5f;
    const float hy = (bound[n * 6 + 4] - bound[n * 6 + 1]) * 0.5f;
    const float hz = (bound[n * 6 + 5] - bound[n * 6 + 2]) * 0.5f;

    const float m00 = invcov[0], m01 = invcov[1], m02 = invcov[2];
    const float m10 = invcov[3], m11 = invcov[4], m12 = invcov[5];
    const float m20 = invcov[6], m21 = invcov[7], m22 = invcov[8];

    // ---- per-lane PSF point ----
    const int pbase = (n * S_PSF + lane) * 3;     // < 2^24*3, fits int
    const float ox = xyz_psf[pbase + 0] * hx;
    const float oy = xyz_psf[pbase + 1] * hy;
    const float oz = xyz_psf[pbase + 2] * hz;

    const float scale = (float)VOL_N / (float)(VOL_N - 1);
    const float ix = (cx + ox) * scale - 0.5f;
    const float iy = (cy + oy) * scale - 0.5f;
    const float iz = (cz + oz) * scale - 0.5f;

    const float x0f = floorf(ix), y0f = floorf(iy), z0f = floorf(iz);
    const float fx = ix - x0f, fy = iy - y0f, fz = iz - z0f;
    const int x0 = (int)x0f, y0 = (int)y0f, z0 = (int)z0f;
    const int x1 = x0 + 1, y1 = y0 + 1, z1 = z0 + 1;

    const bool vx0 = (unsigned)x0 < (unsigned)VOL_N;
    const bool vx1 = (unsigned)x1 < (unsigned)VOL_N;
    const bool vy0 = (unsigned)y0 < (unsigned)VOL_N;
    const bool vy1 = (unsigned)y1 < (unsigned)VOL_N;
    const bool vz0 = (unsigned)z0 < (unsigned)VOL_N;
    const bool vz1 = (unsigned)z1 < (unsigned)VOL_N;

    const float wx0 = 1.0f - fx, wx1 = fx;
    const float wy0 = 1.0f - fy, wy1 = fy;
    const float wz0 = 1.0f - fz, wz1 = fz;

    float v000, v001, v010, v011, v100, v101, v110, v111;
    if (USE_TBL) {
        const int xg = min(max(x0, 0), VOL_N - 1);
        const int yg = min(max(y0, 0), VOL_N - 1);
        const int zg0 = min(max(z0, 0), VOL_N - 1);
        const int zg1 = min(max(z1, 0), VOL_N - 1);
        const int common = (yg << 8) + xg;
        const vh4 p0 = tbl[(zg0 << 16) + common];
        const vh4 p1 = tbl[(zg1 << 16) + common];
        const bool lox = x0 < 0;   // x0==-1 with x1==0 valid
        const bool loy = y0 < 0;
        // slots: {y0x0, y0x1, y1x0, y1x1}; hi-edges are duplicate-baked.
        float s00 = p0.x, s01 = p0.y, s10 = p0.z, s11 = p0.w;
        float a01 = lox ? s00 : s01, a11 = lox ? s10 : s11;
        v000 = s00;                 v001 = a01;
        v010 = loy ? s00 : s10;     v011 = loy ? a01 : a11;
        s00 = p1.x; s01 = p1.y; s10 = p1.z; s11 = p1.w;
        a01 = lox ? s00 : s01; a11 = lox ? s10 : s11;
        v100 = s00;                 v101 = a01;
        v110 = loy ? s00 : s10;     v111 = loy ? a01 : a11;
    } else {
        const int xc0 = min(max(x0, 0), VOL_N - 1);
        const int xc1 = min(max(x1, 0), VOL_N - 1);
        const int yc0 = min(max(y0, 0), VOL_N - 1);
        const int yc1 = min(max(y1, 0), VOL_N - 1);
        const int zc0 = min(max(z0, 0), VOL_N - 1);
        const int zc1 = min(max(z1, 0), VOL_N - 1);
        const int zo0 = zc0 << 16, zo1 = zc1 << 16;
        const int yo0 = yc0 << 8, yo1 = yc1 << 8;
        v000 = vol[zo0 + yo0 + xc0];
        v001 = vol[zo0 + yo0 + xc1];
        v010 = vol[zo0 + yo1 + xc0];
        v011 = vol[zo0 + yo1 + xc1];
        v100 = vol[zo1 + yo0 + xc0];
        v101 = vol[zo1 + yo0 + xc1];
        v110 = vol[zo1 + yo1 + xc0];
        v111 = vol[zo1 + yo1 + xc1];
    }

    float acc = 0.0f;
    acc += (vx0 && vy0 && vz0) ? v000 * (wx0 * wy0 * wz0) : 0.0f;
    acc += (vx1 && vy0 && vz0) ? v001 * (wx1 * wy0 * wz0) : 0.0f;
    acc += (vx0 && vy1 && vz0) ? v010 * (wx0 * wy1 * wz0) : 0.0f;
    acc += (vx1 && vy1 && vz0) ? v011 * (wx1 * wy1 * wz0) : 0.0f;
    acc += (vx0 && vy0 && vz1) ? v100 * (wx0 * wy0 * wz1) : 0.0f;
    acc += (vx1 && vy0 && vz1) ? v101 * (wx1 * wy0 * wz1) : 0.0f;
    acc += (vx0 && vy1 && vz1) ? v110 * (wx0 * wy1 * wz1) : 0.0f;
    acc += (vx1 && vy1 && vz1) ? v111 * (wx1 * wy1 * wz1) : 0.0f;

    const float qx = m00 * ox + m01 * oy + m02 * oz;
    const float qy = m10 * ox + m11 * oy + m12 * oz;
    const float qz = m20 * ox + m21 * oy + m22 * oz;
    const float q = ox * qx + oy * qy + oz * qz;
    const float w = __expf(-0.5f * q);

    float num = acc * w;
    float den = w;
    #pragma unroll
    for (int m = 32; m >= 1; m >>= 1) {
        num += __shfl_xor(num, m, 64);
        den += __shfl_xor(den, m, 64);
    }
    if (lane == 0) out[n] = num / den;
}

extern "C" void kernel_launch(void* const* d_in, const int* in_sizes, int n_in,
                              void* d_out, int out_size, void* d_ws, size_t ws_size,
                              hipStream_t stream) {
    const float* x        = (const float*)d_in[0];
    const float* sg       = (const float*)d_in[1];
    const float* ax       = (const float*)d_in[2];
    const float* bound    = (const float*)d_in[3];
    const float* invcov   = (const float*)d_in[4];
    const float* xyz_psf  = (const float*)d_in[5];
    float* out            = (float*)d_out;

    const int N = in_sizes[1] / 3;           // sampleGrid is [N][3]
    const size_t sort_bytes = (size_t)(2 * NBUCKET + N) * sizeof(int);

    const bool use_tbl  = ws_size >= TBL_BYTES + sort_bytes;
    const bool use_sort = use_tbl || ws_size >= sort_bytes;

    vh4* tbl = use_tbl ? (vh4*)d_ws : nullptr;
    int* sort_ws = use_tbl ? (int*)((char*)d_ws + TBL_BYTES) : (int*)d_ws;

    int* perm = nullptr;
    if (use_sort) {
        zero_hist_kernel<<<(NBUCKET + 255) / 256, 256, 0, stream>>>(sort_ws);
        hist_kernel<<<(N + 255) / 256, 256, 0, stream>>>(sg, sort_ws, N);
        scan_kernel<<<1, 1024, 0, stream>>>(sort_ws);
        scatter_kernel<<<(N + 255) / 256, 256, 0, stream>>>(sg, sort_ws, N);
        perm = sort_ws + 2 * NBUCKET;
    }
    if (use_tbl) {
        build_quad_kernel<<<(VOL_N * VOL_N * VOL_N / 4) / 256, 256, 0, stream>>>(x, tbl);
    }

    dim3 block(256);
    dim3 grid((N + 3) / 4);                  // 4 waves (samples) per block
    if (use_tbl) {
        psf_sample_kernel<true><<<grid, block, 0, stream>>>(
            x, tbl, sg, ax, bound, invcov, xyz_psf, perm, out, N);
    } else {
        psf_sample_kernel<false><<<grid, block, 0, stream>>>(
            x, nullptr, sg, ax, bound, invcov, xyz_psf, perm, out, N);
    }
}

// Round 7
// 322.439 us; speedup vs baseline: 1.4079x; 1.0212x over previous
//
#include <hip/hip_runtime.h>

// Round 7: same as round 6 (scalarized per-sample setup + fp16 quad table +
// spatial sort) but the table-build kernel is rewritten: each thread covers
// TWO entries = exactly one contiguous 16 B store (no 32 B-stride half-line
// pattern), and stores are normal (not nontemporal) so the table stays in
// L2/L3 for the sampling kernel that reads it immediately after.

#define VOL_N 256
#define S_PSF 64
#define NBUCKET 4096   // 16x16x16 cells of 16^3 voxels
#define TBL_ELEMS (1 << 24)                  // 256^3 entries
#define TBL_BYTES ((size_t)TBL_ELEMS * 8)    // 128 MB

typedef float vf4 __attribute__((ext_vector_type(4)));
typedef _Float16 vh4 __attribute__((ext_vector_type(4)));
typedef _Float16 vh8 __attribute__((ext_vector_type(8)));

// ---- d_ws layout ----
// [0, TBL_BYTES)      fp16 quad table (if ws large enough)
// then ints: hist[4096] | offsets[4096] | perm[N]

__device__ __forceinline__ int bucket_of(const float* __restrict__ sg, int n) {
    int cx = min(max((int)sg[n * 3 + 0], 0), VOL_N - 1) >> 4;
    int cy = min(max((int)sg[n * 3 + 1], 0), VOL_N - 1) >> 4;
    int cz = min(max((int)sg[n * 3 + 2], 0), VOL_N - 1) >> 4;
    int m = 0;
    #pragma unroll
    for (int b = 0; b < 4; b++) {
        m |= (((cx >> b) & 1) << (3 * b))
           | (((cy >> b) & 1) << (3 * b + 1))
           | (((cz >> b) & 1) << (3 * b + 2));
    }
    return m;
}

__global__ void zero_hist_kernel(int* __restrict__ ws) {
    int i = blockIdx.x * blockDim.x + threadIdx.x;
    if (i < NBUCKET) ws[i] = 0;
}

__global__ void hist_kernel(const float* __restrict__ sg, int* __restrict__ ws, int N) {
    int n = blockIdx.x * blockDim.x + threadIdx.x;
    if (n >= N) return;
    atomicAdd(&ws[bucket_of(sg, n)], 1);
}

__global__ __launch_bounds__(1024) void scan_kernel(int* __restrict__ ws) {
    __shared__ int tmp[1024];
    const int t = threadIdx.x;
    int h0 = ws[t * 4 + 0], h1 = ws[t * 4 + 1], h2 = ws[t * 4 + 2], h3 = ws[t * 4 + 3];
    int s = h0 + h1 + h2 + h3;
    tmp[t] = s;
    __syncthreads();
    for (int off = 1; off < 1024; off <<= 1) {
        int v = (t >= off) ? tmp[t - off] : 0;
        __syncthreads();
        tmp[t] += v;
        __syncthreads();
    }
    int excl = tmp[t] - s;
    ws[NBUCKET + t * 4 + 0] = excl;
    ws[NBUCKET + t * 4 + 1] = excl + h0;
    ws[NBUCKET + t * 4 + 2] = excl + h0 + h1;
    ws[NBUCKET + t * 4 + 3] = excl + h0 + h1 + h2;
}

__global__ void scatter_kernel(const float* __restrict__ sg, int* __restrict__ ws, int N) {
    int n = blockIdx.x * blockDim.x + threadIdx.x;
    if (n >= N) return;
    int b = bucket_of(sg, n);
    int pos = atomicAdd(&ws[NBUCKET + b], 1);
    ws[2 * NBUCKET + pos] = n;
}

// Build fp16 quad table tbl[z][y][x] = {v[y][x], v[y][x+1], v[y+1][x],
// v[y+1][x+1]} with x=255/y=255 neighbors duplicated. Each thread covers TWO
// consecutive x -> one contiguous 16 B store; consecutive threads contiguous.
__global__ __launch_bounds__(256) void build_quad_kernel(
    const float* __restrict__ vol, vh4* __restrict__ tbl) {
    const int t = blockIdx.x * 256 + threadIdx.x;   // [0, 256*256*128)
    const int x2 = (t & 127) << 1;
    const int y = (t >> 7) & 255;
    const int z = t >> 15;
    const float* r0 = vol + (z << 16) + (y << 8);
    const float* r1 = vol + (z << 16) + (min(y + 1, VOL_N - 1) << 8);
    const float2 a = *(const float2*)(r0 + x2);
    const float2 b = *(const float2*)(r1 + x2);
    const float a2 = (x2 == VOL_N - 2) ? a.y : r0[x2 + 2];
    const float b2 = (x2 == VOL_N - 2) ? b.y : r1[x2 + 2];

    union { vh8 h; vf4 f; } o;
    o.h = (vh8){(_Float16)a.x, (_Float16)a.y, (_Float16)b.x, (_Float16)b.y,
                (_Float16)a.y, (_Float16)a2,  (_Float16)b.y, (_Float16)b2};
    *(vf4*)(tbl + ((z << 16) + (y << 8) + x2)) = o.f;
}

template <bool USE_TBL>
__global__ __launch_bounds__(256, 4) void psf_sample_kernel(
    const float* __restrict__ vol,        // [256][256][256] (z,y,x)
    const vh4* __restrict__ tbl,          // fp16 quad table (USE_TBL)
    const float* __restrict__ sampleGrid, // [N][3]
    const float* __restrict__ ax,         // [N][6]
    const float* __restrict__ bound,      // [N][2][3]
    const float* __restrict__ invcov,     // [3][3]
    const float* __restrict__ xyz_psf,    // [N][64][3]
    const int* __restrict__ perm,         // sorted pos -> n (or null)
    float* __restrict__ out,              // [N]
    int N)
{
    const int lane = threadIdx.x & 63;

    // XCD-contiguous swizzle so each XCD sweeps a contiguous sorted range
    int bid = blockIdx.x;
    const int nb = gridDim.x;
    if ((nb & 7) == 0) bid = (bid & 7) * (nb >> 3) + (bid >> 3);

    const int i = bid * (blockDim.x >> 6) + (threadIdx.x >> 6);
    if (i >= N) return;
    // n is wave-uniform; force it into an SGPR so all per-sample parameter
    // loads become s_load (SMEM) instead of 64-lane broadcast vector loads.
    const int n = __builtin_amdgcn_readfirstlane(perm ? perm[i] : i);

    // ---- wave-uniform per-sample setup (scalar loads, uniform math) ----
    const float vx = ax[n * 6 + 0], vy = ax[n * 6 + 1], vz = ax[n * 6 + 2];
    const float tx = ax[n * 6 + 3], ty = ax[n * 6 + 4], tz = ax[n * 6 + 5];

    const float theta = sqrtf(vx * vx + vy * vy + vz * vz);
    const float kinv = 1.0f / fmaxf(theta, 1e-12f);
    const float kx = vx * kinv, ky = vy * kinv, kz = vz * kinv;
    const float ct = __cosf(theta), st = __sinf(theta);
    const float oc = 1.0f - ct;

    const float r00 = 1.0f + oc * (-(ky * ky + kz * kz));
    const float r01 = -st * kz + oc * kx * ky;
    const float r02 =  st * ky + oc * kx * kz;
    const float r10 =  st * kz + oc * kx * ky;
    const float r11 = 1.0f + oc * (-(kx * kx + kz * kz));
    const float r12 = -st * kx + oc * ky * kz;
    const float r20 = -st * ky + oc * kx * kz;
    const float r21 =  st * kx + oc * ky * kz;
    const float r22 = 1.0f + oc * (-(kx * kx + ky * ky));

    const float px = sampleGrid[n * 3 + 0] + tx;
    const float py = sampleGrid[n * 3 + 1] + ty;
    const float pz = sampleGrid[n * 3 + 2] + tz;

    const float cx = r00 * px + r01 * py + r02 * pz;
    const float cy = r10 * px + r11 * py + r12 * pz;
    const float cz = r20 * px + r21 * py + r22 * pz;

    const float hx = (bound[n * 6 + 3] - bound[n * 6 + 0]) * 0.5f;
    const float hy = (bound[n * 6 + 4] - bound[n * 6 + 1]) * 0.5f;
    const float hz = (bound[n * 6 + 5] - bound[n * 6 + 2]) * 0.5f;

    const float m00 = invcov[0], m01 = invcov[1], m02 = invcov[2];
    const float m10 = invcov[3], m11 = invcov[4], m12 = invcov[5];
    const float m20 = invcov[6], m21 = invcov[7], m22 = invcov[8];

    // ---- per-lane PSF point ----
    const int pbase = (n * S_PSF + lane) * 3;     // < 2^24*3, fits int
    const float ox = xyz_psf[pbase + 0] * hx;
    const float oy = xyz_psf[pbase + 1] * hy;
    const float oz = xyz_psf[pbase + 2] * hz;

    const float scale = (float)VOL_N / (float)(VOL_N - 1);
    const float ix = (cx + ox) * scale - 0.5f;
    const float iy = (cy + oy) * scale - 0.5f;
    const float iz = (cz + oz) * scale - 0.5f;

    const float x0f = floorf(ix), y0f = floorf(iy), z0f = floorf(iz);
    const float fx = ix - x0f, fy = iy - y0f, fz = iz - z0f;
    const int x0 = (int)x0f, y0 = (int)y0f, z0 = (int)z0f;
    const int x1 = x0 + 1, y1 = y0 + 1, z1 = z0 + 1;

    const bool vx0 = (unsigned)x0 < (unsigned)VOL_N;
    const bool vx1 = (unsigned)x1 < (unsigned)VOL_N;
    const bool vy0 = (unsigned)y0 < (unsigned)VOL_N;
    const bool vy1 = (unsigned)y1 < (unsigned)VOL_N;
    const bool vz0 = (unsigned)z0 < (unsigned)VOL_N;
    const bool vz1 = (unsigned)z1 < (unsigned)VOL_N;

    const float wx0 = 1.0f - fx, wx1 = fx;
    const float wy0 = 1.0f - fy, wy1 = fy;
    const float wz0 = 1.0f - fz, wz1 = fz;

    float v000, v001, v010, v011, v100, v101, v110, v111;
    if (USE_TBL) {
        const int xg = min(max(x0, 0), VOL_N - 1);
        const int yg = min(max(y0, 0), VOL_N - 1);
        const int zg0 = min(max(z0, 0), VOL_N - 1);
        const int zg1 = min(max(z1, 0), VOL_N - 1);
        const int common = (yg << 8) + xg;
        const vh4 p0 = tbl[(zg0 << 16) + common];
        const vh4 p1 = tbl[(zg1 << 16) + common];
        const bool lox = x0 < 0;   // x0==-1 with x1==0 valid
        const bool loy = y0 < 0;
        // slots: {y0x0, y0x1, y1x0, y1x1}; hi-edges are duplicate-baked.
        float s00 = p0.x, s01 = p0.y, s10 = p0.z, s11 = p0.w;
        float a01 = lox ? s00 : s01, a11 = lox ? s10 : s11;
        v000 = s00;                 v001 = a01;
        v010 = loy ? s00 : s10;     v011 = loy ? a01 : a11;
        s00 = p1.x; s01 = p1.y; s10 = p1.z; s11 = p1.w;
        a01 = lox ? s00 : s01; a11 = lox ? s10 : s11;
        v100 = s00;                 v101 = a01;
        v110 = loy ? s00 : s10;     v111 = loy ? a01 : a11;
    } else {
        const int xc0 = min(max(x0, 0), VOL_N - 1);
        const int xc1 = min(max(x1, 0), VOL_N - 1);
        const int yc0 = min(max(y0, 0), VOL_N - 1);
        const int yc1 = min(max(y1, 0), VOL_N - 1);
        const int zc0 = min(max(z0, 0), VOL_N - 1);
        const int zc1 = min(max(z1, 0), VOL_N - 1);
        const int zo0 = zc0 << 16, zo1 = zc1 << 16;
        const int yo0 = yc0 << 8, yo1 = yc1 << 8;
        v000 = vol[zo0 + yo0 + xc0];
        v001 = vol[zo0 + yo0 + xc1];
        v010 = vol[zo0 + yo1 + xc0];
        v011 = vol[zo0 + yo1 + xc1];
        v100 = vol[zo1 + yo0 + xc0];
        v101 = vol[zo1 + yo0 + xc1];
        v110 = vol[zo1 + yo1 + xc0];
        v111 = vol[zo1 + yo1 + xc1];
    }

    float acc = 0.0f;
    acc += (vx0 && vy0 && vz0) ? v000 * (wx0 * wy0 * wz0) : 0.0f;
    acc += (vx1 && vy0 && vz0) ? v001 * (wx1 * wy0 * wz0) : 0.0f;
    acc += (vx0 && vy1 && vz0) ? v010 * (wx0 * wy1 * wz0) : 0.0f;
    acc += (vx1 && vy1 && vz0) ? v011 * (wx1 * wy1 * wz0) : 0.0f;
    acc += (vx0 && vy0 && vz1) ? v100 * (wx0 * wy0 * wz1) : 0.0f;
    acc += (vx1 && vy0 && vz1) ? v101 * (wx1 * wy0 * wz1) : 0.0f;
    acc += (vx0 && vy1 && vz1) ? v110 * (wx0 * wy1 * wz1) : 0.0f;
    acc += (vx1 && vy1 && vz1) ? v111 * (wx1 * wy1 * wz1) : 0.0f;

    const float qx = m00 * ox + m01 * oy + m02 * oz;
    const float qy = m10 * ox + m11 * oy + m12 * oz;
    const float qz = m20 * ox + m21 * oy + m22 * oz;
    const float q = ox * qx + oy * qy + oz * qz;
    const float w = __expf(-0.5f * q);

    float num = acc * w;
    float den = w;
    #pragma unroll
    for (int m = 32; m >= 1; m >>= 1) {
        num += __shfl_xor(num, m, 64);
        den += __shfl_xor(den, m, 64);
    }
    if (lane == 0) out[n] = num / den;
}

extern "C" void kernel_launch(void* const* d_in, const int* in_sizes, int n_in,
                              void* d_out, int out_size, void* d_ws, size_t ws_size,
                              hipStream_t stream) {
    const float* x        = (const float*)d_in[0];
    const float* sg       = (const float*)d_in[1];
    const float* ax       = (const float*)d_in[2];
    const float* bound    = (const float*)d_in[3];
    const float* invcov   = (const float*)d_in[4];
    const float* xyz_psf  = (const float*)d_in[5];
    float* out            = (float*)d_out;

    const int N = in_sizes[1] / 3;           // sampleGrid is [N][3]
    const size_t sort_bytes = (size_t)(2 * NBUCKET + N) * sizeof(int);

    const bool use_tbl  = ws_size >= TBL_BYTES + sort_bytes;
    const bool use_sort = use_tbl || ws_size >= sort_bytes;

    vh4* tbl = use_tbl ? (vh4*)d_ws : nullptr;
    int* sort_ws = use_tbl ? (int*)((char*)d_ws + TBL_BYTES) : (int*)d_ws;

    int* perm = nullptr;
    if (use_sort) {
        zero_hist_kernel<<<(NBUCKET + 255) / 256, 256, 0, stream>>>(sort_ws);
        hist_kernel<<<(N + 255) / 256, 256, 0, stream>>>(sg, sort_ws, N);
        scan_kernel<<<1, 1024, 0, stream>>>(sort_ws);
        scatter_kernel<<<(N + 255) / 256, 256, 0, stream>>>(sg, sort_ws, N);
        perm = sort_ws + 2 * NBUCKET;
    }
    if (use_tbl) {
        build_quad_kernel<<<(VOL_N * VOL_N * VOL_N / 2) / 256, 256, 0, stream>>>(x, tbl);
    }

    dim3 block(256);
    dim3 grid((N + 3) / 4);                  // 4 waves (samples) per block
    if (use_tbl) {
        psf_sample_kernel<true><<<grid, block, 0, stream>>>(
            x, tbl, sg, ax, bound, invcov, xyz_psf, perm, out, N);
    } else {
        psf_sample_kernel<false><<<grid, block, 0, stream>>>(
            x, nullptr, sg, ax, bound, invcov, xyz_psf, perm, out, N);
    }
}